// Round 9
// baseline (81.322 us; speedup 1.0000x reference)
//
#include <hip/hip_runtime.h>

// AnatomicalConsistencyLoss: fused separable-Sobel magnitude + cosine loss.
// pred/target (2,1,160,160,160) f32 -> scalar f32.
// R9: BARRIER-FREE main loop. R8 showed the per-plane barrier lockstep (not
// prefetch depth) was the limiter. Each thread now computes horizontal combos
// for its own 3 rows (y-1,y,y+1) straight from global loads (L1/L2 serve the
// 3x row reuse; HBM unchanged), so LDS + __syncthreads vanish from the loop.
// z-direction keeps R6's streaming pending-sum (28 dwords, named scalars).
// 2-deep ping-pong register prefetch (~2 planes of latency cover), waves run
// free -- latency hidden by TLP + prefetch, no lockstep.

constexpr int Dd = 160, Hh = 160, Ww = 160;
constexpr int TW = 32, TH = 16, DC = 8;
constexpr int NTX = Ww / TW;                 // 5
constexpr int NTY = Hh / TH;                 // 10
constexpr int NB_X = NTX * NTY;              // 50
constexpr int NB_Y = Dd / DC;                // 20
constexpr int NB_Z = 2;
constexpr int NBLOCKS = NB_X * NB_Y * NB_Z;  // 2000
constexpr int PLANES = DC + 2;               // 10 (even: x2 unroll)
constexpr int PLSZ = Hh * Ww;                // 25600
constexpr double NVOX = 2.0 * Dd * Hh * Ww;  // 8,192,000

__device__ __forceinline__ float2 sm3f2(const float2 a, const float2 b, const float2 c) {
    return make_float2(a.x + 2.f*b.x + c.x, a.y + 2.f*b.y + c.y);
}
__device__ __forceinline__ float2 df2f2(const float2 a, const float2 c) {
    return make_float2(c.x - a.x, c.y - a.y);
}
__device__ __forceinline__ float2 add2(const float2 a, const float2 b) {
    return make_float2(a.x + b.x, a.y + b.y);
}
__device__ __forceinline__ float2 fma2s(const float2 a, const float s, const float2 b) {
    return make_float2(fmaf(a.x, s, b.x), fmaf(a.y, s, b.y));
}
__device__ __forceinline__ float2 neg2(const float2 a) {
    return make_float2(-a.x, -a.y);
}

// horizontal 1D combos from a float2 + left/right halo via lane shuffle.
// gx==0 / gx==15 lanes (where shfl crosses a row boundary) use their own
// edge-scalar; all lanes execute the shfl (wave-uniform).
__device__ __forceinline__ void combo2(const float2 v, const float el, const float er,
                                       const bool eLo, const bool eHi,
                                       float2& HS, float2& HD) {
    float e0 = __shfl_up(v.y, 1);
    if (eLo) e0 = el;
    float e2 = __shfl_down(v.x, 1);
    if (eHi) e2 = er;
    HS = make_float2(e0 + 2.f*v.x + v.y, v.x + 2.f*v.y + e2);
    HD = make_float2(v.y - e0, e2 - v.x);
}

struct PF {   // one plane's prefetched values: 3 rows x 2 vols (24 dwords)
    float2 mP, cP, pP, mT, cT, pT;          // rows y-1, y, y+1
    float lmP, lcP, lpP, lmT, lcT, lpT;     // left-edge scalars
    float rmP, rcP, rpP, rmT, rcT, rpT;     // right-edge scalars
};

__global__ __launch_bounds__(256)
void acl_partial(const float* __restrict__ pred, const float* __restrict__ targ,
                 float2* __restrict__ partial)
{
    __shared__ float rred[8];   // final reduction only; no LDS in main loop

    const int tid = threadIdx.x;
    const int gx = tid & 15;          // x-group of 2 floats
    const int r  = tid >> 4;          // row 0..15

    const int wt = blockIdx.x % NTX;
    const int ht = blockIdx.x / NTX;
    const int x0 = wt * TW, y0 = ht * TH;
    const int z0 = blockIdx.y * DC;
    const size_t base = (size_t)blockIdx.z * ((size_t)Dd * PLSZ);
    const float* __restrict__ pv = pred + base;
    const float* __restrict__ tv = targ + base;

    const int X = x0 + 2 * gx;
    const bool eLo = (gx == 0);
    const bool eHi = (gx == 15);
    const bool xm  = (x0 > 0);
    const bool xp  = (x0 + TW < Ww);

    const int gym = y0 + r - 1;                    // -1..158
    const int gyp = y0 + r + 1;                    // 1..160
    const bool yokm = (gym >= 0);
    const bool yokp = (gyp < Hh);
    const int om = gym * Ww + X;
    const int oc = (y0 + r) * Ww + X;              // always in-bounds
    const int op = gyp * Ww + X;

    const float2 z2 = make_float2(0.f, 0.f);

    // streaming pending partial gradients (named scalars only)
    float2 P1x = z2, P1y = z2, P1z = z2, P2x = z2, P2y = z2, P2z = z2;  // pred
    float2 T1x = z2, T1y = z2, T1z = z2, T2x = z2, T2y = z2, T2z = z2;  // targ
    float2 accm = z2, accc = z2;

    auto issue = [&](PF& f, int p) {
        const int gz = z0 - 1 + p;
        const bool zok = (unsigned)gz < (unsigned)Dd;   // wave-uniform
        const float* pz = pv + (ptrdiff_t)gz * PLSZ;
        const float* tz = tv + (ptrdiff_t)gz * PLSZ;
        f.mP = f.cP = f.pP = f.mT = f.cT = f.pT = z2;
        f.lmP = f.lcP = f.lpP = f.lmT = f.lcT = f.lpT = 0.f;
        f.rmP = f.rcP = f.rpP = f.rmT = f.rcT = f.rpT = 0.f;
        if (zok) {
            if (yokm) {
                f.mP = *(const float2*)(pz + om);
                f.mT = *(const float2*)(tz + om);
                if (eLo && xm) { f.lmP = pz[om - 1]; f.lmT = tz[om - 1]; }
                if (eHi && xp) { f.rmP = pz[om + 2]; f.rmT = tz[om + 2]; }
            }
            {
                f.cP = *(const float2*)(pz + oc);
                f.cT = *(const float2*)(tz + oc);
                if (eLo && xm) { f.lcP = pz[oc - 1]; f.lcT = tz[oc - 1]; }
                if (eHi && xp) { f.rcP = pz[oc + 2]; f.rcT = tz[oc + 2]; }
            }
            if (yokp) {
                f.pP = *(const float2*)(pz + op);
                f.pT = *(const float2*)(tz + op);
                if (eLo && xm) { f.lpP = pz[op - 1]; f.lpT = tz[op - 1]; }
                if (eHi && xp) { f.rpP = pz[op + 2]; f.rpT = tz[op + 2]; }
            }
        }
    };

    auto step = [&](PF& f, int p) {
        float2 HSm, HDm, HS0, HD0, HSp, HDp;

        // ---- pred: own-row horizontal combos -> vertical -> stream ----
        combo2(f.mP, f.lmP, f.rmP, eLo, eHi, HSm, HDm);
        combo2(f.cP, f.lcP, f.rcP, eLo, eHi, HS0, HD0);
        combo2(f.pP, f.lpP, f.rpP, eLo, eHi, HSp, HDp);
        float2 A = sm3f2(HSm, HS0, HSp);   // sm_y(sm_x) -> z-deriv path
        float2 B = sm3f2(HDm, HD0, HDp);   // sm_y(d_x)  -> x-gradient
        float2 C = df2f2(HSm, HSp);        // d_y(sm_x)  -> y-gradient
        const float2 fpx = add2(P1x, B), fpy = add2(P1y, C), fpz = add2(P1z, A);
        P1x = fma2s(B, 2.f, P2x);  P1y = fma2s(C, 2.f, P2y);  P1z = P2z;
        P2x = B;  P2y = C;  P2z = neg2(A);

        // ---- targ ----
        combo2(f.mT, f.lmT, f.rmT, eLo, eHi, HSm, HDm);
        combo2(f.cT, f.lcT, f.rcT, eLo, eHi, HS0, HD0);
        combo2(f.pT, f.lpT, f.rpT, eLo, eHi, HSp, HDp);
        A = sm3f2(HSm, HS0, HSp);
        B = sm3f2(HDm, HD0, HDp);
        C = df2f2(HSm, HSp);
        const float2 ftx = add2(T1x, B), fty = add2(T1y, C), ftz = add2(T1z, A);
        T1x = fma2s(B, 2.f, T2x);  T1y = fma2s(C, 2.f, T2y);  T1z = T2z;
        T2x = B;  T2y = C;  T2z = neg2(A);

        if (p >= 2) {   // output plane z0 + (p-2) finalized
            #define LOSS_COMP(c)                                                  \
            {                                                                     \
                const float np2 = fpx.c*fpx.c + fpy.c*fpy.c + fpz.c*fpz.c;        \
                const float nt2 = ftx.c*ftx.c + fty.c*fty.c + ftz.c*ftz.c;        \
                const float pm = __builtin_amdgcn_sqrtf(np2 + 1e-8f);             \
                const float tm = __builtin_amdgcn_sqrtf(nt2 + 1e-8f);             \
                const float dm = pm - tm;                                         \
                accm.c += dm * dm;                                                \
                const float dt = fpx.c*ftx.c + fpy.c*fty.c + fpz.c*ftz.c;         \
                const float ra = __builtin_amdgcn_rsqf(fmaxf(np2, 1e-30f));       \
                const float rb = __builtin_amdgcn_rsqf(fmaxf(nt2, 1e-30f));       \
                accc.c += dt * ra * rb;                                           \
            }
            LOSS_COMP(x)
            LOSS_COMP(y)
            #undef LOSS_COMP
        }
    };

    PF f0, f1;
    issue(f0, 0);
    issue(f1, 1);

    #pragma unroll
    for (int pp = 0; pp < PLANES; pp += 2) {   // ping-pong: ~2 planes of cover
        step(f0, pp);
        if (pp + 2 < PLANES) issue(f0, pp + 2);
        step(f1, pp + 1);
        if (pp + 3 < PLANES) issue(f1, pp + 3);
    }

    // ---- block reduction (only sync in the kernel) ----
    float am = accm.x + accm.y;
    float ac = accc.x + accc.y;
    #pragma unroll
    for (int off = 32; off >= 1; off >>= 1) {
        am += __shfl_down(am, off);
        ac += __shfl_down(ac, off);
    }
    const int wid = tid >> 6;
    if ((tid & 63) == 0) { rred[wid] = am; rred[4 + wid] = ac; }
    __syncthreads();
    if (tid == 0) {
        const float m = rred[0] + rred[1] + rred[2] + rred[3];
        const float c = rred[4] + rred[5] + rred[6] + rred[7];
        const int bid = (blockIdx.z * gridDim.y + blockIdx.y) * gridDim.x + blockIdx.x;
        partial[bid] = make_float2(m, c);
    }
}

__global__ __launch_bounds__(256)
void acl_final(const float2* __restrict__ partial, float* __restrict__ out)
{
    __shared__ double sm[256], sc[256];
    double m = 0.0, c = 0.0;
    for (int i = threadIdx.x; i < NBLOCKS; i += 256) {
        const float2 v = partial[i];
        m += (double)v.x;
        c += (double)v.y;
    }
    sm[threadIdx.x] = m;
    sc[threadIdx.x] = c;
    __syncthreads();
    #pragma unroll
    for (int s = 128; s >= 1; s >>= 1) {
        if (threadIdx.x < (unsigned)s) {
            sm[threadIdx.x] += sm[threadIdx.x + s];
            sc[threadIdx.x] += sc[threadIdx.x + s];
        }
        __syncthreads();
    }
    if (threadIdx.x == 0) {
        const double mag_loss = sm[0] / NVOX;
        const double dir_loss = 1.0 - sc[0] / NVOX;
        out[0] = (float)(0.2 * (mag_loss + dir_loss));
    }
}

extern "C" void kernel_launch(void* const* d_in, const int* in_sizes, int n_in,
                              void* d_out, int out_size, void* d_ws, size_t ws_size,
                              hipStream_t stream) {
    const float* pred = (const float*)d_in[0];
    const float* targ = (const float*)d_in[1];
    float* out = (float*)d_out;
    float2* partial = (float2*)d_ws;  // 2000 * 8 B = 16 KB

    dim3 grid(NB_X, NB_Y, NB_Z);  // (50, 20, 2)
    acl_partial<<<grid, 256, 0, stream>>>(pred, targ, partial);
    acl_final<<<1, 256, 0, stream>>>(partial, out);
}

// Round 10
// 46.411 us; speedup vs baseline: 1.7522x; 1.7522x over previous
//
#include <hip/hip_runtime.h>

// AnatomicalConsistencyLoss: fused separable-Sobel magnitude + cosine loss.
// pred/target (2,1,160,160,160) f32 -> scalar f32.
// R10: barrier-free loop (R9) with REGISTER-MINIMAL loads. R9's failure was
// VGPR=176 -> 11% occupancy, caused by 18 conditional edge scalars per PF
// set. Fix: one 4B-aligned (misaligned) float4 load per row spanning
// [X-1..X+2] -- 6 loads/plane/thread, no shfl, no edge scalars. x-volume
// edges handled by per-lane offset clamp + 4-wide select in the two
// block-uniform edge-block cases only. Half-plane software pipeline:
// issue targ -> consume pred -> issue next pred -> consume targ; 6 loads in
// flight steady-state. Streaming pending-sum z-state (named float2 scalars,
// R6). amdgpu_waves_per_eu(4) caps VGPR at 128 (pressure ~90: no spill).

constexpr int Dd = 160, Hh = 160, Ww = 160;
constexpr int TW = 32, TH = 16, DC = 8;
constexpr int NTX = Ww / TW;                 // 5
constexpr int NTY = Hh / TH;                 // 10
constexpr int NB_X = NTX * NTY;              // 50
constexpr int NB_Y = Dd / DC;                // 20
constexpr int NB_Z = 2;
constexpr int NBLOCKS = NB_X * NB_Y * NB_Z;  // 2000
constexpr int PLANES = DC + 2;               // 10
constexpr int PLSZ = Hh * Ww;                // 25600
constexpr double NVOX = 2.0 * Dd * Hh * Ww;  // 8,192,000

// 4-byte-aligned float4: hardware supports dword-aligned global_load_dwordx4.
typedef float f4 __attribute__((ext_vector_type(4), aligned(4)));

__device__ __forceinline__ float2 sm3f2(const float2 a, const float2 b, const float2 c) {
    return make_float2(a.x + 2.f*b.x + c.x, a.y + 2.f*b.y + c.y);
}
__device__ __forceinline__ float2 df2f2(const float2 a, const float2 c) {
    return make_float2(c.x - a.x, c.y - a.y);
}
__device__ __forceinline__ float2 add2(const float2 a, const float2 b) {
    return make_float2(a.x + b.x, a.y + b.y);
}
__device__ __forceinline__ float2 fma2s(const float2 a, const float s, const float2 b) {
    return make_float2(fmaf(a.x, s, b.x), fmaf(a.y, s, b.y));
}
__device__ __forceinline__ float2 neg2(const float2 a) {
    return make_float2(-a.x, -a.y);
}

// horizontal combos from raw span e = [e(X-1), e(X), e(X+1), e(X+2)]
__device__ __forceinline__ void comboF4(const f4 e, float2& HS, float2& HD) {
    HS = make_float2(e.x + 2.f*e.y + e.z, e.y + 2.f*e.z + e.w);
    HD = make_float2(e.z - e.x, e.w - e.y);
}

__attribute__((amdgpu_waves_per_eu(4)))
__global__ __launch_bounds__(256)
void acl_partial(const float* __restrict__ pred, const float* __restrict__ targ,
                 float2* __restrict__ partial)
{
    __shared__ float rred[8];   // final reduction only; no LDS in main loop

    const int tid = threadIdx.x;
    const int gx = tid & 15;          // x-group of 2 output cols
    const int r  = tid >> 4;          // row 0..15

    const int wt = blockIdx.x % NTX;
    const int ht = blockIdx.x / NTX;
    const int x0 = wt * TW, y0 = ht * TH;
    const int z0 = blockIdx.y * DC;
    const size_t base = (size_t)blockIdx.z * ((size_t)Dd * PLSZ);
    const float* __restrict__ pv = pred + base;
    const float* __restrict__ tv = targ + base;

    const int X = x0 + 2 * gx;
    const bool blkLo = (x0 == 0);
    const bool blkHi = (x0 + TW == Ww);
    const bool fixLo = blkLo && (gx == 0);    // load clamped +1, shift-right fixup
    const bool fixHi = blkHi && (gx == 15);   // load clamped -1, shift-left fixup
    const int xoff = X - 1 + (fixLo ? 1 : 0) - (fixHi ? 1 : 0);

    const int gym = y0 + r - 1;
    const int gyp = y0 + r + 1;
    const bool yokm = (gym >= 0);
    const bool yokp = (gyp < Hh);
    const int om = gym * Ww + xoff;
    const int oc = (y0 + r) * Ww + xoff;
    const int op = gyp * Ww + xoff;

    const float2 z2 = make_float2(0.f, 0.f);
    const f4 z4 = {0.f, 0.f, 0.f, 0.f};

    // streaming pending partial gradients (named scalars only)
    float2 P1x = z2, P1y = z2, P1z = z2, P2x = z2, P2y = z2, P2z = z2;  // pred
    float2 T1x = z2, T1y = z2, T1z = z2, T2x = z2, T2y = z2, T2z = z2;  // targ
    float2 accm = z2, accc = z2;

    // prefetch registers: 3 rows per volume (24 dwords total)
    f4 mP, cP, pP, mT, cT, pT;

    auto issueP = [&](int p) {
        const int gz = z0 - 1 + p;
        mP = cP = pP = z4;
        if ((unsigned)gz < (unsigned)Dd) {            // wave-uniform
            const float* pz = pv + (ptrdiff_t)gz * PLSZ;
            if (yokm) mP = *(const f4*)(pz + om);
            cP = *(const f4*)(pz + oc);
            if (yokp) pP = *(const f4*)(pz + op);
        }
    };
    auto issueT = [&](int p) {
        const int gz = z0 - 1 + p;
        mT = cT = pT = z4;
        if ((unsigned)gz < (unsigned)Dd) {
            const float* tz = tv + (ptrdiff_t)gz * PLSZ;
            if (yokm) mT = *(const f4*)(tz + om);
            cT = *(const f4*)(tz + oc);
            if (yokp) pT = *(const f4*)(tz + op);
        }
    };

    // volume-edge fixup: only edge blocks pay (block-uniform branches)
    auto fixup = [&](f4 v) -> f4 {
        if (blkLo) { const f4 s = {0.f, v.x, v.y, v.z}; if (fixLo) v = s; }
        if (blkHi) { const f4 s = {v.y, v.z, v.w, 0.f}; if (fixHi) v = s; }
        return v;
    };

    auto consumeVol = [&](f4 m, f4 c, f4 p, float2& A, float2& B, float2& C) {
        m = fixup(m); c = fixup(c); p = fixup(p);
        float2 HSm, HDm, HS0, HD0, HSp, HDp;
        comboF4(m, HSm, HDm);
        comboF4(c, HS0, HD0);
        comboF4(p, HSp, HDp);
        A = sm3f2(HSm, HS0, HSp);   // sm_y(sm_x) -> z-deriv path
        B = sm3f2(HDm, HD0, HDp);   // sm_y(d_x)  -> x-gradient
        C = df2f2(HSm, HSp);        // d_y(sm_x)  -> y-gradient
    };

    issueP(0);

    for (int p = 0; p < PLANES; ++p) {
        issueT(p);                      // targ loads fly under pred consume

        float2 A, B, C;
        consumeVol(mP, cP, pP, A, B, C);
        const float2 fpx = add2(P1x, B), fpy = add2(P1y, C), fpz = add2(P1z, A);
        P1x = fma2s(B, 2.f, P2x);  P1y = fma2s(C, 2.f, P2y);  P1z = P2z;
        P2x = B;  P2y = C;  P2z = neg2(A);

        if (p + 1 < PLANES) issueP(p + 1);   // next pred flies under targ consume

        consumeVol(mT, cT, pT, A, B, C);
        const float2 ftx = add2(T1x, B), fty = add2(T1y, C), ftz = add2(T1z, A);
        T1x = fma2s(B, 2.f, T2x);  T1y = fma2s(C, 2.f, T2y);  T1z = T2z;
        T2x = B;  T2y = C;  T2z = neg2(A);

        if (p >= 2) {   // output plane z0 + (p-2) finalized
            #define LOSS_COMP(c)                                                  \
            {                                                                     \
                const float np2 = fpx.c*fpx.c + fpy.c*fpy.c + fpz.c*fpz.c;        \
                const float nt2 = ftx.c*ftx.c + fty.c*fty.c + ftz.c*ftz.c;        \
                const float pm = __builtin_amdgcn_sqrtf(np2 + 1e-8f);             \
                const float tm = __builtin_amdgcn_sqrtf(nt2 + 1e-8f);             \
                const float dm = pm - tm;                                         \
                accm.c += dm * dm;                                                \
                const float dt = fpx.c*ftx.c + fpy.c*fty.c + fpz.c*ftz.c;         \
                const float ra = __builtin_amdgcn_rsqf(fmaxf(np2, 1e-30f));       \
                const float rb = __builtin_amdgcn_rsqf(fmaxf(nt2, 1e-30f));       \
                accc.c += dt * ra * rb;                                           \
            }
            LOSS_COMP(x)
            LOSS_COMP(y)
            #undef LOSS_COMP
        }
    }

    // ---- block reduction (only sync in the kernel) ----
    float am = accm.x + accm.y;
    float ac = accc.x + accc.y;
    #pragma unroll
    for (int off = 32; off >= 1; off >>= 1) {
        am += __shfl_down(am, off);
        ac += __shfl_down(ac, off);
    }
    const int wid = tid >> 6;
    if ((tid & 63) == 0) { rred[wid] = am; rred[4 + wid] = ac; }
    __syncthreads();
    if (tid == 0) {
        const float m = rred[0] + rred[1] + rred[2] + rred[3];
        const float c = rred[4] + rred[5] + rred[6] + rred[7];
        const int bid = (blockIdx.z * gridDim.y + blockIdx.y) * gridDim.x + blockIdx.x;
        partial[bid] = make_float2(m, c);
    }
}

__global__ __launch_bounds__(256)
void acl_final(const float2* __restrict__ partial, float* __restrict__ out)
{
    __shared__ double sm[256], sc[256];
    double m = 0.0, c = 0.0;
    for (int i = threadIdx.x; i < NBLOCKS; i += 256) {
        const float2 v = partial[i];
        m += (double)v.x;
        c += (double)v.y;
    }
    sm[threadIdx.x] = m;
    sc[threadIdx.x] = c;
    __syncthreads();
    #pragma unroll
    for (int s = 128; s >= 1; s >>= 1) {
        if (threadIdx.x < (unsigned)s) {
            sm[threadIdx.x] += sm[threadIdx.x + s];
            sc[threadIdx.x] += sc[threadIdx.x + s];
        }
        __syncthreads();
    }
    if (threadIdx.x == 0) {
        const double mag_loss = sm[0] / NVOX;
        const double dir_loss = 1.0 - sc[0] / NVOX;
        out[0] = (float)(0.2 * (mag_loss + dir_loss));
    }
}

extern "C" void kernel_launch(void* const* d_in, const int* in_sizes, int n_in,
                              void* d_out, int out_size, void* d_ws, size_t ws_size,
                              hipStream_t stream) {
    const float* pred = (const float*)d_in[0];
    const float* targ = (const float*)d_in[1];
    float* out = (float*)d_out;
    float2* partial = (float2*)d_ws;  // 2000 * 8 B = 16 KB

    dim3 grid(NB_X, NB_Y, NB_Z);  // (50, 20, 2)
    acl_partial<<<grid, 256, 0, stream>>>(pred, targ, partial);
    acl_final<<<1, 256, 0, stream>>>(partial, out);
}

// Round 11
// 38.744 us; speedup vs baseline: 2.0990x; 1.1979x over previous
//
#include <hip/hip_runtime.h>

// AnatomicalConsistencyLoss: fused separable-Sobel magnitude + cosine loss.
// pred/target (2,1,160,160,160) f32 -> scalar f32.
// R11 = R10 body (barrier-free, f4 misaligned row loads, streaming
// pending-sum, 40 VGPR no-spill) + XCD-chunked bijective block swizzle:
// 1D grid 2000 = 8 XCDs x 250; decode order zt(fastest), wt, ht, b so each
// XCD owns contiguous (all-z x all-x) slabs (~3.7MB ~ L2/XCD) and halo-
// sharing neighbor blocks are co-XCD + co-resident -> z/x halos hit L2 not
// HBM. Plus transcendental fusion: (pm-tm)^2 = a+b-2*sqrt(ab),
// rsq(np2)*rsq(nt2) = rsq(np2*nt2) -- halves quarter-rate trans ops.

constexpr int Dd = 160, Hh = 160, Ww = 160;
constexpr int TW = 32, TH = 16, DC = 8;
constexpr int NTX = Ww / TW;                 // 5
constexpr int NTY = Hh / TH;                 // 10
constexpr int NTZ = Dd / DC;                 // 20
constexpr int NBLOCKS = NTX * NTY * NTZ * 2; // 2000
constexpr int NXCD = 8;
constexpr int CHUNK = NBLOCKS / NXCD;        // 250 (2000 % 8 == 0: bijective)
constexpr int PLANES = DC + 2;               // 10
constexpr int PLSZ = Hh * Ww;                // 25600
constexpr double NVOX = 2.0 * Dd * Hh * Ww;  // 8,192,000

// 4-byte-aligned float4: hardware supports dword-aligned global_load_dwordx4.
typedef float f4 __attribute__((ext_vector_type(4), aligned(4)));

__device__ __forceinline__ float2 sm3f2(const float2 a, const float2 b, const float2 c) {
    return make_float2(a.x + 2.f*b.x + c.x, a.y + 2.f*b.y + c.y);
}
__device__ __forceinline__ float2 df2f2(const float2 a, const float2 c) {
    return make_float2(c.x - a.x, c.y - a.y);
}
__device__ __forceinline__ float2 add2(const float2 a, const float2 b) {
    return make_float2(a.x + b.x, a.y + b.y);
}
__device__ __forceinline__ float2 fma2s(const float2 a, const float s, const float2 b) {
    return make_float2(fmaf(a.x, s, b.x), fmaf(a.y, s, b.y));
}
__device__ __forceinline__ float2 neg2(const float2 a) {
    return make_float2(-a.x, -a.y);
}

// horizontal combos from raw span e = [e(X-1), e(X), e(X+1), e(X+2)]
__device__ __forceinline__ void comboF4(const f4 e, float2& HS, float2& HD) {
    HS = make_float2(e.x + 2.f*e.y + e.z, e.y + 2.f*e.z + e.w);
    HD = make_float2(e.z - e.x, e.w - e.y);
}

__attribute__((amdgpu_waves_per_eu(4)))
__global__ __launch_bounds__(256)
void acl_partial(const float* __restrict__ pred, const float* __restrict__ targ,
                 float2* __restrict__ partial)
{
    __shared__ float rred[8];   // final reduction only; no LDS in main loop

    const int tid = threadIdx.x;
    const int gx = tid & 15;          // x-group of 2 output cols
    const int r  = tid >> 4;          // row 0..15

    // ---- XCD-chunked bijective swizzle + decode (zt fastest, wt, ht, b) ----
    const int bid  = blockIdx.x;
    const int swz  = (bid % NXCD) * CHUNK + bid / NXCD;   // XCD k owns [k*250, ...)
    const int zt   = swz % NTZ;
    const int t1   = swz / NTZ;          // 0..99
    const int wt   = t1 % NTX;
    const int t2   = t1 / NTX;           // 0..19
    const int ht   = t2 % NTY;
    const int b    = t2 / NTY;           // 0..1

    const int x0 = wt * TW, y0 = ht * TH;
    const int z0 = zt * DC;
    const size_t base = (size_t)b * ((size_t)Dd * PLSZ);
    const float* __restrict__ pv = pred + base;
    const float* __restrict__ tv = targ + base;

    const int X = x0 + 2 * gx;
    const bool blkLo = (x0 == 0);
    const bool blkHi = (x0 + TW == Ww);
    const bool fixLo = blkLo && (gx == 0);    // load clamped +1, shift-right fixup
    const bool fixHi = blkHi && (gx == 15);   // load clamped -1, shift-left fixup
    const int xoff = X - 1 + (fixLo ? 1 : 0) - (fixHi ? 1 : 0);

    const int gym = y0 + r - 1;
    const int gyp = y0 + r + 1;
    const bool yokm = (gym >= 0);
    const bool yokp = (gyp < Hh);
    const int om = gym * Ww + xoff;
    const int oc = (y0 + r) * Ww + xoff;
    const int op = gyp * Ww + xoff;

    const float2 z2 = make_float2(0.f, 0.f);
    const f4 z4 = {0.f, 0.f, 0.f, 0.f};

    // streaming pending partial gradients (named scalars only)
    float2 P1x = z2, P1y = z2, P1z = z2, P2x = z2, P2y = z2, P2z = z2;  // pred
    float2 T1x = z2, T1y = z2, T1z = z2, T2x = z2, T2y = z2, T2z = z2;  // targ
    float2 accm = z2, accc = z2;

    // prefetch registers: 3 rows per volume (24 dwords total)
    f4 mP, cP, pP, mT, cT, pT;

    auto issueP = [&](int p) {
        const int gz = z0 - 1 + p;
        mP = cP = pP = z4;
        if ((unsigned)gz < (unsigned)Dd) {            // wave-uniform
            const float* pz = pv + (ptrdiff_t)gz * PLSZ;
            if (yokm) mP = *(const f4*)(pz + om);
            cP = *(const f4*)(pz + oc);
            if (yokp) pP = *(const f4*)(pz + op);
        }
    };
    auto issueT = [&](int p) {
        const int gz = z0 - 1 + p;
        mT = cT = pT = z4;
        if ((unsigned)gz < (unsigned)Dd) {
            const float* tz = tv + (ptrdiff_t)gz * PLSZ;
            if (yokm) mT = *(const f4*)(tz + om);
            cT = *(const f4*)(tz + oc);
            if (yokp) pT = *(const f4*)(tz + op);
        }
    };

    // volume-edge fixup: only edge blocks pay (block-uniform branches)
    auto fixup = [&](f4 v) -> f4 {
        if (blkLo) { const f4 s = {0.f, v.x, v.y, v.z}; if (fixLo) v = s; }
        if (blkHi) { const f4 s = {v.y, v.z, v.w, 0.f}; if (fixHi) v = s; }
        return v;
    };

    auto consumeVol = [&](f4 m, f4 c, f4 p, float2& A, float2& B, float2& C) {
        m = fixup(m); c = fixup(c); p = fixup(p);
        float2 HSm, HDm, HS0, HD0, HSp, HDp;
        comboF4(m, HSm, HDm);
        comboF4(c, HS0, HD0);
        comboF4(p, HSp, HDp);
        A = sm3f2(HSm, HS0, HSp);   // sm_y(sm_x) -> z-deriv path
        B = sm3f2(HDm, HD0, HDp);   // sm_y(d_x)  -> x-gradient
        C = df2f2(HSm, HSp);        // d_y(sm_x)  -> y-gradient
    };

    issueP(0);

    for (int p = 0; p < PLANES; ++p) {
        issueT(p);                      // targ loads fly under pred consume

        float2 A, B, C;
        consumeVol(mP, cP, pP, A, B, C);
        const float2 fpx = add2(P1x, B), fpy = add2(P1y, C), fpz = add2(P1z, A);
        P1x = fma2s(B, 2.f, P2x);  P1y = fma2s(C, 2.f, P2y);  P1z = P2z;
        P2x = B;  P2y = C;  P2z = neg2(A);

        if (p + 1 < PLANES) issueP(p + 1);   // next pred flies under targ consume

        consumeVol(mT, cT, pT, A, B, C);
        const float2 ftx = add2(T1x, B), fty = add2(T1y, C), ftz = add2(T1z, A);
        T1x = fma2s(B, 2.f, T2x);  T1y = fma2s(C, 2.f, T2y);  T1z = T2z;
        T2x = B;  T2y = C;  T2z = neg2(A);

        if (p >= 2) {   // output plane z0 + (p-2) finalized
            // fused: (pm-tm)^2 = a+b-2*sqrt(a*b);  rsq(np2)*rsq(nt2)=rsq(np2*nt2)
            #define LOSS_COMP(c)                                                  \
            {                                                                     \
                const float np2 = fpx.c*fpx.c + fpy.c*fpy.c + fpz.c*fpz.c;        \
                const float nt2 = ftx.c*ftx.c + fty.c*fty.c + ftz.c*ftz.c;        \
                const float a = np2 + 1e-8f, bb = nt2 + 1e-8f;                    \
                accm.c += a + bb - 2.f * __builtin_amdgcn_sqrtf(a * bb);          \
                const float dt = fpx.c*ftx.c + fpy.c*fty.c + fpz.c*ftz.c;         \
                const float pr = fmaxf(np2 * nt2, 1e-30f);                        \
                accc.c += dt * __builtin_amdgcn_rsqf(pr);                         \
            }
            LOSS_COMP(x)
            LOSS_COMP(y)
            #undef LOSS_COMP
        }
    }

    // ---- block reduction (only sync in the kernel) ----
    float am = accm.x + accm.y;
    float ac = accc.x + accc.y;
    #pragma unroll
    for (int off = 32; off >= 1; off >>= 1) {
        am += __shfl_down(am, off);
        ac += __shfl_down(ac, off);
    }
    const int wid = tid >> 6;
    if ((tid & 63) == 0) { rred[wid] = am; rred[4 + wid] = ac; }
    __syncthreads();
    if (tid == 0) {
        const float m = rred[0] + rred[1] + rred[2] + rred[3];
        const float c = rred[4] + rred[5] + rred[6] + rred[7];
        partial[bid] = make_float2(m, c);   // any unique slot; final sums all
    }
}

__global__ __launch_bounds__(256)
void acl_final(const float2* __restrict__ partial, float* __restrict__ out)
{
    __shared__ double sm[256], sc[256];
    double m = 0.0, c = 0.0;
    for (int i = threadIdx.x; i < NBLOCKS; i += 256) {
        const float2 v = partial[i];
        m += (double)v.x;
        c += (double)v.y;
    }
    sm[threadIdx.x] = m;
    sc[threadIdx.x] = c;
    __syncthreads();
    #pragma unroll
    for (int s = 128; s >= 1; s >>= 1) {
        if (threadIdx.x < (unsigned)s) {
            sm[threadIdx.x] += sm[threadIdx.x + s];
            sc[threadIdx.x] += sc[threadIdx.x + s];
        }
        __syncthreads();
    }
    if (threadIdx.x == 0) {
        const double mag_loss = sm[0] / NVOX;
        const double dir_loss = 1.0 - sc[0] / NVOX;
        out[0] = (float)(0.2 * (mag_loss + dir_loss));
    }
}

extern "C" void kernel_launch(void* const* d_in, const int* in_sizes, int n_in,
                              void* d_out, int out_size, void* d_ws, size_t ws_size,
                              hipStream_t stream) {
    const float* pred = (const float*)d_in[0];
    const float* targ = (const float*)d_in[1];
    float* out = (float*)d_out;
    float2* partial = (float2*)d_ws;  // 2000 * 8 B = 16 KB

    acl_partial<<<NBLOCKS, 256, 0, stream>>>(pred, targ, partial);
    acl_final<<<1, 256, 0, stream>>>(partial, out);
}